// Round 5
// baseline (308.648 us; speedup 1.0000x reference)
//
#include <hip/hip_runtime.h>
#include <stdint.h>

#define NN 16384
#define NE 128

typedef __attribute__((ext_vector_type(8))) short bf16x8;
typedef __attribute__((ext_vector_type(4))) float f32x4;

__device__ __forceinline__ uint32_t pack_bf16_2(float a, float b){
  union { float f; uint32_t u; } ua, ub;
  ua.f = a; ub.f = b;
  uint32_t x = ua.u, y = ub.u;
  x = (x + 0x7fffu + ((x >> 16) & 1u)) >> 16;   // RNE
  y = (y + 0x7fffu + ((y >> 16) & 1u)) >> 16;
  return (x & 0xffffu) | (y << 16);
}

// A [NN][NE] fp32 -> Ab [NN][NE] bf16
__global__ void conv_a_kernel(const float4* __restrict__ A, uint4* __restrict__ Ab){
  size_t t = (size_t)blockIdx.x * blockDim.x + threadIdx.x;
  float4 a = A[2*t], b = A[2*t+1];
  uint4 o;
  o.x = pack_bf16_2(a.x, a.y);
  o.y = pack_bf16_2(a.z, a.w);
  o.z = pack_bf16_2(b.x, b.y);
  o.w = pack_bf16_2(b.z, b.w);
  Ab[t] = o;
}

// B [NE][NN] fp32 + W[NE] -> Bt [NN][NE] bf16, Bt[n][k] = bf16(W[k]*B[k][n])
__global__ void conv_bt_kernel(const float* __restrict__ B, const float* __restrict__ W,
                               uint4* __restrict__ Bt){
  int n = blockIdx.x * 256 + threadIdx.x;
  #pragma unroll
  for (int kc = 0; kc < 16; ++kc){
    float f[8];
    #pragma unroll
    for (int j = 0; j < 8; ++j){
      int k = kc*8 + j;
      f[j] = W[k] * B[(size_t)k * NN + n];    // coalesced along n
    }
    uint4 o;
    o.x = pack_bf16_2(f[0], f[1]);
    o.y = pack_bf16_2(f[2], f[3]);
    o.z = pack_bf16_2(f[4], f[5]);
    o.w = pack_bf16_2(f[6], f[7]);
    Bt[(size_t)n * 16 + kc] = o;
  }
}

// R5: NO LDS, NO BARRIERS. Each wave loads its MFMA fragments directly from
// L2-resident Ab/Bt (4MB each) and free-runs: stage/compute/store phases of
// the ~12 resident waves/CU decorrelate, keeping the HBM write pipe
// continuously fed (R4 post-mortem: 2-block/CU barrier-gated structure left
// the store pipe idle ~30% of the time; fill kernel proves 6.5TB/s needs only
// continuous issue, not occupancy).
// Grid (unchanged from v3): GM=16 m-tiles/group; group's 512KB Ab slice stays
// L2-hot across all 128 n-panels, 16 consecutive bids share one Bt panel.
// Epilogue (unchanged from v3): normal write-back dword stores; 4 consecutive
// insts cover a 256B row span, L2 assembles full lines.
__launch_bounds__(256, 3)
__global__ void gemm_kernel(const uint4* __restrict__ Ab, const uint4* __restrict__ Bt,
                            float* __restrict__ C){
  const int tid  = threadIdx.x;
  const int lane = tid & 63;
  const int bid  = blockIdx.x;
  const int grp  = bid >> 11;            // bid / (16*128): 8 groups
  const int r    = bid & 2047;
  const int m0   = (((grp << 4) + (r & 15)) << 7);   // m iterates fastest within group
  const int n0   = ((r >> 4) << 7);

  const int w   = tid >> 6;
  const int wm  = (w >> 1) << 6;         // wave's 64-row block
  const int wn  = (w & 1) << 6;          // wave's 64-col block
  const int l15 = lane & 15;
  const int l4  = lane >> 4;

  // Per-lane fragment base addresses (16B chunks): row*16 + chunk
  const uint4* abase = Ab + (((size_t)(m0 + wm + l15)) << 4) + l4;
  const uint4* bbase = Bt + (((size_t)(n0 + wn + l15)) << 4) + l4;

  f32x4 acc[4][4];
  #pragma unroll
  for (int i = 0; i < 4; ++i)
    #pragma unroll
    for (int j = 0; j < 4; ++j)
      acc[i][j] = (f32x4){0.f, 0.f, 0.f, 0.f};

  #pragma unroll
  for (int ks = 0; ks < 4; ++ks){        // K = 4 x 32
    bf16x8 af[4], bfr[4];
    #pragma unroll
    for (int mt = 0; mt < 4; ++mt)       // wave reads 16 rows x 64B per frag set
      af[mt] = *reinterpret_cast<const bf16x8*>(abase + ((size_t)(mt << 4) << 4) + (ks << 2));
    #pragma unroll
    for (int nt = 0; nt < 4; ++nt)
      bfr[nt] = *reinterpret_cast<const bf16x8*>(bbase + ((size_t)(nt << 4) << 4) + (ks << 2));
    #pragma unroll
    for (int mt = 0; mt < 4; ++mt)
      #pragma unroll
      for (int nt = 0; nt < 4; ++nt)
        acc[mt][nt] = __builtin_amdgcn_mfma_f32_16x16x32_bf16(af[mt], bfr[nt], acc[mt][nt], 0, 0, 0);
  }

  // C/D layout: col = lane&15, row = (lane>>4)*4 + reg. Direct dword stores.
  #pragma unroll
  for (int mt = 0; mt < 4; ++mt){
    #pragma unroll
    for (int j = 0; j < 4; ++j){
      size_t row = (size_t)(m0 + wm + (mt << 4) + (l4 << 2) + j);
      float* crow = C + row * NN + (size_t)(n0 + wn + l15);
      #pragma unroll
      for (int nt = 0; nt < 4; ++nt)
        crow[nt << 4] = acc[mt][nt][j];
    }
  }
}

// correctness fallback if workspace is too small (fp32 vector math, slow but exact-path)
__global__ void gemm_fallback(const float* __restrict__ A, const float* __restrict__ B,
                              const float* __restrict__ W, float* __restrict__ C){
  int n = blockIdx.x * 16 + threadIdx.x;
  int m = blockIdx.y * 16 + threadIdx.y;
  float acc = 0.f;
  for (int k = 0; k < NE; ++k)
    acc += A[(size_t)m * NE + k] * (W[k] * B[(size_t)k * NN + n]);
  C[(size_t)m * NN + n] = acc;
}

extern "C" void kernel_launch(void* const* d_in, const int* in_sizes, int n_in,
                              void* d_out, int out_size, void* d_ws, size_t ws_size,
                              hipStream_t stream){
  const float* A = (const float*)d_in[0];   // DV2_H [NN][NE]
  const float* B = (const float*)d_in[1];   // invDE_HT_DV2 [NE][NN]
  const float* W = (const float*)d_in[2];   // [NE]
  float* C = (float*)d_out;                 // [NN][NN] fp32

  const size_t need = (size_t)NN * NE * 2 * 2;   // Ab + Bt, 8 MB
  if (ws_size >= need){
    uint4* Ab = (uint4*)d_ws;
    uint4* Bt = (uint4*)((char*)d_ws + (size_t)NN * NE * 2);
    conv_a_kernel<<<NN * NE / (256 * 8), 256, 0, stream>>>((const float4*)A, Ab);
    conv_bt_kernel<<<NN / 256, 256, 0, stream>>>(B, W, Bt);
    gemm_kernel<<<(NN / 128) * (NN / 128), 256, 0, stream>>>(Ab, Bt, C);
  } else {
    dim3 g(NN / 16, NN / 16), b(16, 16);
    gemm_fallback<<<g, b, 0, stream>>>(A, B, W, C);
  }
}

// Round 6
// 227.082 us; speedup vs baseline: 1.3592x; 1.3592x over previous
//
#include <hip/hip_runtime.h>
#include <stdint.h>

#define NN 16384
#define NE 128

typedef __attribute__((ext_vector_type(8))) short bf16x8;
typedef __attribute__((ext_vector_type(4))) float f32x4;
typedef uint32_t __attribute__((address_space(1))) gl_u32;
typedef uint32_t __attribute__((address_space(3))) lds_u32;

__device__ __forceinline__ uint32_t pack_bf16_2(float a, float b){
  union { float f; uint32_t u; } ua, ub;
  ua.f = a; ub.f = b;
  uint32_t x = ua.u, y = ub.u;
  x = (x + 0x7fffu + ((x >> 16) & 1u)) >> 16;   // RNE
  y = (y + 0x7fffu + ((y >> 16) & 1u)) >> 16;
  return (x & 0xffffu) | (y << 16);
}

// A [NN][NE] fp32 -> Ab [NN][NE] bf16
__global__ void conv_a_kernel(const float4* __restrict__ A, uint4* __restrict__ Ab){
  size_t t = (size_t)blockIdx.x * blockDim.x + threadIdx.x;
  float4 a = A[2*t], b = A[2*t+1];
  uint4 o;
  o.x = pack_bf16_2(a.x, a.y);
  o.y = pack_bf16_2(a.z, a.w);
  o.z = pack_bf16_2(b.x, b.y);
  o.w = pack_bf16_2(b.z, b.w);
  Ab[t] = o;
}

// B [NE][NN] fp32 + W[NE] -> Bt [NN][NE] bf16, Bt[n][k] = bf16(W[k]*B[k][n])
__global__ void conv_bt_kernel(const float* __restrict__ B, const float* __restrict__ W,
                               uint4* __restrict__ Bt){
  int n = blockIdx.x * 256 + threadIdx.x;
  #pragma unroll
  for (int kc = 0; kc < 16; ++kc){
    float f[8];
    #pragma unroll
    for (int j = 0; j < 8; ++j){
      int k = kc*8 + j;
      f[j] = W[k] * B[(size_t)k * NN + n];    // coalesced along n
    }
    uint4 o;
    o.x = pack_bf16_2(f[0], f[1]);
    o.y = pack_bf16_2(f[2], f[3]);
    o.z = pack_bf16_2(f[4], f[5]);
    o.w = pack_bf16_2(f[6], f[7]);
    Bt[(size_t)n * 16 + kc] = o;
  }
}

// v3 structure (best: 226us) + ONE change: staging via global_load_lds width=16
// (drops 16 ds_write wave-insts/wave from the LDS pipe + the VGPR round-trip;
// R5 post-mortem arithmetic: stage+LDS pipeline is the ~1.7us/pair that isn't
// hidden behind the 5us/pair store drain at 2 blocks/CU).
// Operand LDS: 16B chunks, physical slot (row, g) holds logical chunk g^(row&7);
// global_load_lds dest is linear (base+lane*16), swizzle carried on the per-lane
// SOURCE address; reads apply the same XOR (involution) -> rule-21-correct.
__launch_bounds__(256, 2)
__global__ void gemm_kernel(const uint4* __restrict__ Ab, const uint4* __restrict__ Bt,
                            float* __restrict__ C){
  __shared__ uint4 lds[4096];            // 64 KB: [0..2047] A-tile, [2048..4095] B-tile
  const int tid  = threadIdx.x;
  const int lane = tid & 63;
  const int bid  = blockIdx.x;
  const int grp  = bid >> 11;            // bid / (16*128): 8 groups
  const int r    = bid & 2047;
  const int m0   = (((grp << 4) + (r & 15)) << 7);   // m iterates fastest within group
  const int n0   = ((r >> 4) << 7);

  // stage both tiles: 16 direct-to-LDS DMA loads per thread, swizzled source
  #pragma unroll
  for (int i = 0; i < 8; ++i){
    int cid = (i << 8) + tid;            // 0..2047 : row = cid>>4, g = cid&15
    int row = cid >> 4;
    int gs  = (cid & 15) ^ (row & 7);    // source logical chunk for this physical slot
    __builtin_amdgcn_global_load_lds((const gl_u32*)(Ab + (((size_t)(m0 + row)) << 4) + gs),
                                     (lds_u32*)&lds[cid], 16, 0, 0);
    __builtin_amdgcn_global_load_lds((const gl_u32*)(Bt + (((size_t)(n0 + row)) << 4) + gs),
                                     (lds_u32*)&lds[2048 + cid], 16, 0, 0);
  }
  __syncthreads();                       // drains vmcnt -> LDS data visible

  const int w   = tid >> 6;
  const int wm  = (w >> 1) << 6;         // wave's 64-row block
  const int wn  = (w & 1) << 6;          // wave's 64-col block
  const int l15 = lane & 15;
  const int l4  = lane >> 4;

  f32x4 acc[4][4];
  #pragma unroll
  for (int i = 0; i < 4; ++i)
    #pragma unroll
    for (int j = 0; j < 4; ++j)
      acc[i][j] = (f32x4){0.f, 0.f, 0.f, 0.f};

  #pragma unroll
  for (int ks = 0; ks < 4; ++ks){        // K = 4 x 32
    bf16x8 af[4], bfr[4];
    const int c = (ks << 2) + l4;        // logical 16B chunk = 8 k-values
    #pragma unroll
    for (int mt = 0; mt < 4; ++mt){
      int row = wm + (mt << 4) + l15;    // A row (lane&15 = M index)
      af[mt] = *reinterpret_cast<const bf16x8*>(&lds[(row << 4) + (c ^ (row & 7))]);
    }
    #pragma unroll
    for (int nt = 0; nt < 4; ++nt){
      int row = wn + (nt << 4) + l15;    // Bt row (lane&15 = N index)
      bfr[nt] = *reinterpret_cast<const bf16x8*>(&lds[2048 + (row << 4) + (c ^ (row & 7))]);
    }
    #pragma unroll
    for (int mt = 0; mt < 4; ++mt)
      #pragma unroll
      for (int nt = 0; nt < 4; ++nt)
        acc[mt][nt] = __builtin_amdgcn_mfma_f32_16x16x32_bf16(af[mt], bfr[nt], acc[mt][nt], 0, 0, 0);
  }

  // C/D layout: col = lane&15, row = (lane>>4)*4 + reg. Direct dword stores
  // (R2 showed LDS-transpose epilogue regresses at 2 blocks/CU). 4 consecutive
  // insts cover a contiguous 256B span per row; L2 write-back assembles lines.
  #pragma unroll
  for (int mt = 0; mt < 4; ++mt){
    #pragma unroll
    for (int j = 0; j < 4; ++j){
      size_t row = (size_t)(m0 + wm + (mt << 4) + (l4 << 2) + j);
      float* crow = C + row * NN + (size_t)(n0 + wn + l15);
      #pragma unroll
      for (int nt = 0; nt < 4; ++nt)
        crow[nt << 4] = acc[mt][nt][j];
    }
  }
}

// correctness fallback if workspace is too small (fp32 vector math, slow but exact-path)
__global__ void gemm_fallback(const float* __restrict__ A, const float* __restrict__ B,
                              const float* __restrict__ W, float* __restrict__ C){
  int n = blockIdx.x * 16 + threadIdx.x;
  int m = blockIdx.y * 16 + threadIdx.y;
  float acc = 0.f;
  for (int k = 0; k < NE; ++k)
    acc += A[(size_t)m * NE + k] * (W[k] * B[(size_t)k * NN + n]);
  C[(size_t)m * NN + n] = acc;
}

extern "C" void kernel_launch(void* const* d_in, const int* in_sizes, int n_in,
                              void* d_out, int out_size, void* d_ws, size_t ws_size,
                              hipStream_t stream){
  const float* A = (const float*)d_in[0];   // DV2_H [NN][NE]
  const float* B = (const float*)d_in[1];   // invDE_HT_DV2 [NE][NN]
  const float* W = (const float*)d_in[2];   // [NE]
  float* C = (float*)d_out;                 // [NN][NN] fp32

  const size_t need = (size_t)NN * NE * 2 * 2;   // Ab + Bt, 8 MB
  if (ws_size >= need){
    uint4* Ab = (uint4*)d_ws;
    uint4* Bt = (uint4*)((char*)d_ws + (size_t)NN * NE * 2);
    conv_a_kernel<<<NN * NE / (256 * 8), 256, 0, stream>>>((const float4*)A, Ab);
    conv_bt_kernel<<<NN / 256, 256, 0, stream>>>(B, W, Bt);
    gemm_kernel<<<(NN / 128) * (NN / 128), 256, 0, stream>>>(Ab, Bt, C);
  } else {
    dim3 g(NN / 16, NN / 16), b(16, 16);
    gemm_fallback<<<g, b, 0, stream>>>(A, B, W, C);
  }
}

// Round 7
// 217.628 us; speedup vs baseline: 1.4182x; 1.0434x over previous
//
#include <hip/hip_runtime.h>
#include <stdint.h>

#define NN 16384
#define NE 128

typedef __attribute__((ext_vector_type(8))) short bf16x8;
typedef __attribute__((ext_vector_type(4))) float f32x4;
typedef uint32_t __attribute__((address_space(1))) gl_u32;
typedef uint32_t __attribute__((address_space(3))) lds_u32;

__device__ __forceinline__ uint32_t pack_bf16_2(float a, float b){
  union { float f; uint32_t u; } ua, ub;
  ua.f = a; ub.f = b;
  uint32_t x = ua.u, y = ub.u;
  x = (x + 0x7fffu + ((x >> 16) & 1u)) >> 16;   // RNE
  y = (y + 0x7fffu + ((y >> 16) & 1u)) >> 16;
  return (x & 0xffffu) | (y << 16);
}

// A [NN][NE] fp32 -> Ab [NN][NE] bf16
__global__ void conv_a_kernel(const float4* __restrict__ A, uint4* __restrict__ Ab){
  size_t t = (size_t)blockIdx.x * blockDim.x + threadIdx.x;
  float4 a = A[2*t], b = A[2*t+1];
  uint4 o;
  o.x = pack_bf16_2(a.x, a.y);
  o.y = pack_bf16_2(a.z, a.w);
  o.z = pack_bf16_2(b.x, b.y);
  o.w = pack_bf16_2(b.z, b.w);
  Ab[t] = o;
}

// B [NE][NN] fp32 + W[NE] -> Bt [NN][NE] bf16, Bt[n][k] = bf16(W[k]*B[k][n])
__global__ void conv_bt_kernel(const float* __restrict__ B, const float* __restrict__ W,
                               uint4* __restrict__ Bt){
  int n = blockIdx.x * 256 + threadIdx.x;
  #pragma unroll
  for (int kc = 0; kc < 16; ++kc){
    float f[8];
    #pragma unroll
    for (int j = 0; j < 8; ++j){
      int k = kc*8 + j;
      f[j] = W[k] * B[(size_t)k * NN + n];    // coalesced along n
    }
    uint4 o;
    o.x = pack_bf16_2(f[0], f[1]);
    o.y = pack_bf16_2(f[2], f[3]);
    o.z = pack_bf16_2(f[4], f[5]);
    o.w = pack_bf16_2(f[6], f[7]);
    Bt[(size_t)n * 16 + kc] = o;
  }
}

// R7: 128x64 tile -> 48KB LDS -> 3 blocks/CU (was 2 at 64KB). Single variable:
// per-CU phase granularity. 3 independently-phased blocks keep the HBM store
// pipe continuously fed (R6 post-mortem: with 2 barrier-gated blocks/CU the
// write pipe idles whenever both are in stage/compute phase; store pattern,
// operand traffic, L2 allocation, and staging path were all eliminated as
// suspects in R2-R6).
// Everything else unchanged: XOR-swizzled LDS (rule 21: linear gload_lds dest
// + inverse-swz source + swz read), R3 grouping (GM=16 m-tiles/group), direct
// dword C-stores (4 consecutive insts = 256B row span, L2 assembles lines).
__launch_bounds__(256, 3)
__global__ void gemm_kernel(const uint4* __restrict__ Ab, const uint4* __restrict__ Bt,
                            float* __restrict__ C){
  __shared__ uint4 lds[3072];            // 48 KB: [0..2047] A 128rows, [2048..3071] B 64rows
  const int tid  = threadIdx.x;
  const int lane = tid & 63;
  const int bid  = blockIdx.x;
  const int grp  = bid >> 12;            // bid / (16*256): 8 groups
  const int r    = bid & 4095;
  const int m0   = (((grp << 4) + (r & 15)) << 7);   // m iterates fastest within group
  const int n0   = ((r >> 4) << 6);                  // 256 n-panels of 64

  // stage A-tile (8 chunks/thread) + B-tile (4 chunks/thread), swizzled source
  #pragma unroll
  for (int i = 0; i < 8; ++i){
    int cid = (i << 8) + tid;            // 0..2047 : row = cid>>4, g = cid&15
    int row = cid >> 4;
    int gs  = (cid & 15) ^ (row & 7);
    __builtin_amdgcn_global_load_lds((const gl_u32*)(Ab + (((size_t)(m0 + row)) << 4) + gs),
                                     (lds_u32*)&lds[cid], 16, 0, 0);
  }
  #pragma unroll
  for (int i = 0; i < 4; ++i){
    int cid = (i << 8) + tid;            // 0..1023 : row = cid>>4, g = cid&15
    int row = cid >> 4;
    int gs  = (cid & 15) ^ (row & 7);
    __builtin_amdgcn_global_load_lds((const gl_u32*)(Bt + (((size_t)(n0 + row)) << 4) + gs),
                                     (lds_u32*)&lds[2048 + cid], 16, 0, 0);
  }
  __syncthreads();                       // drains vmcnt -> LDS data visible

  const int w   = tid >> 6;
  const int wm  = (w >> 1) << 6;         // wave's 64-row block (2x2 wave grid)
  const int wn  = (w & 1) << 5;          // wave's 32-col block
  const int l15 = lane & 15;
  const int l4  = lane >> 4;

  f32x4 acc[4][2];
  #pragma unroll
  for (int i = 0; i < 4; ++i)
    #pragma unroll
    for (int j = 0; j < 2; ++j)
      acc[i][j] = (f32x4){0.f, 0.f, 0.f, 0.f};

  #pragma unroll
  for (int ks = 0; ks < 4; ++ks){        // K = 4 x 32
    bf16x8 af[4], bfr[2];
    const int c = (ks << 2) + l4;        // logical 16B chunk = 8 k-values
    #pragma unroll
    for (int mt = 0; mt < 4; ++mt){
      int row = wm + (mt << 4) + l15;    // A row (lane&15 = M index)
      af[mt] = *reinterpret_cast<const bf16x8*>(&lds[(row << 4) + (c ^ (row & 7))]);
    }
    #pragma unroll
    for (int nt = 0; nt < 2; ++nt){
      int row = wn + (nt << 4) + l15;    // Bt row (lane&15 = N index)
      bfr[nt] = *reinterpret_cast<const bf16x8*>(&lds[2048 + (row << 4) + (c ^ (row & 7))]);
    }
    #pragma unroll
    for (int mt = 0; mt < 4; ++mt)
      #pragma unroll
      for (int nt = 0; nt < 2; ++nt)
        acc[mt][nt] = __builtin_amdgcn_mfma_f32_16x16x32_bf16(af[mt], bfr[nt], acc[mt][nt], 0, 0, 0);
  }

  // C/D layout: col = lane&15 (n), row = (lane>>4)*4 + reg (m).
  #pragma unroll
  for (int mt = 0; mt < 4; ++mt){
    #pragma unroll
    for (int j = 0; j < 4; ++j){
      size_t row = (size_t)(m0 + wm + (mt << 4) + (l4 << 2) + j);
      float* crow = C + row * NN + (size_t)(n0 + wn + l15);
      #pragma unroll
      for (int nt = 0; nt < 2; ++nt)
        crow[nt << 4] = acc[mt][nt][j];
    }
  }
}

// correctness fallback if workspace is too small (fp32 vector math, slow but exact-path)
__global__ void gemm_fallback(const float* __restrict__ A, const float* __restrict__ B,
                              const float* __restrict__ W, float* __restrict__ C){
  int n = blockIdx.x * 16 + threadIdx.x;
  int m = blockIdx.y * 16 + threadIdx.y;
  float acc = 0.f;
  for (int k = 0; k < NE; ++k)
    acc += A[(size_t)m * NE + k] * (W[k] * B[(size_t)k * NN + n]);
  C[(size_t)m * NN + n] = acc;
}

extern "C" void kernel_launch(void* const* d_in, const int* in_sizes, int n_in,
                              void* d_out, int out_size, void* d_ws, size_t ws_size,
                              hipStream_t stream){
  const float* A = (const float*)d_in[0];   // DV2_H [NN][NE]
  const float* B = (const float*)d_in[1];   // invDE_HT_DV2 [NE][NN]
  const float* W = (const float*)d_in[2];   // [NE]
  float* C = (float*)d_out;                 // [NN][NN] fp32

  const size_t need = (size_t)NN * NE * 2 * 2;   // Ab + Bt, 8 MB
  if (ws_size >= need){
    uint4* Ab = (uint4*)d_ws;
    uint4* Bt = (uint4*)((char*)d_ws + (size_t)NN * NE * 2);
    conv_a_kernel<<<NN * NE / (256 * 8), 256, 0, stream>>>((const float4*)A, Ab);
    conv_bt_kernel<<<NN / 256, 256, 0, stream>>>(B, W, Bt);
    gemm_kernel<<<(NN / 128) * (NN / 64), 256, 0, stream>>>(Ab, Bt, C);
  } else {
    dim3 g(NN / 16, NN / 16), b(16, 16);
    gemm_fallback<<<g, b, 0, stream>>>(A, B, W, C);
  }
}